// Round 9
// baseline (186.203 us; speedup 1.0000x reference)
//
#include <hip/hip_runtime.h>
#include <math.h>

#define BB 2
#define CC 256
#define LL 512   // H == W == L
#define N4 33554432   // output float4 quads

typedef float v4f __attribute__((ext_vector_type(4)));

__device__ __forceinline__ float gelu_exact(float x) {
    return 0.5f * x * (1.0f + erff(x * 0.70710678118654752f));
}

// ---------------- K1: fused diag-gather + grouped conv1 (+GELU) -> x1,
//                  w2 transpose -> w2t, zero ALL output quads ----------------
__global__ __launch_bounds__(256) void k1(
    const float* __restrict__ feat, const float* __restrict__ w1,
    const float* __restrict__ b1, const float* __restrict__ w2,
    float* __restrict__ x1, float* __restrict__ w2t, v4f* __restrict__ out)
{
    const int tid = threadIdx.x;
    const int blk = blockIdx.x;
    if (blk >= 1024) {                       // zero blocks: one thread = one quad
        int idx4 = (blk - 1024) * 256 + tid; // [0, N4)
        __builtin_nontemporal_store((v4f)(0.f), &out[idx4]);
        return;
    }
    if (blk < 256) {
        __shared__ float sg[32][34];
        int b  = blk >> 7;
        int g  = (blk >> 4) & 7;
        int l0 = (blk & 15) << 5;
        for (int t = tid; t < 32 * 34; t += 256) {
            int ch = t / 34;
            int j  = t - ch * 34;
            int l  = l0 + j - 1;
            int c  = (g << 5) + ch;
            sg[ch][j] = (l >= 0 && l < LL) ? feat[((b * CC + c) * LL + l) * LL + l] : 0.f;
        }
        __syncthreads();
        int ll = tid & 31;
        int os = tid >> 5;
        float a0[4] = {0.f, 0.f, 0.f, 0.f};
        float a1[4] = {0.f, 0.f, 0.f, 0.f};
        float a2[4] = {0.f, 0.f, 0.f, 0.f};
        const float* wbase = w1 + ((g << 5) + (os << 2)) * 96;
        #pragma unroll
        for (int i = 0; i < 32; ++i) {
            float dm = sg[i][ll];
            float d0 = sg[i][ll + 1];
            float dp = sg[i][ll + 2];
            #pragma unroll
            for (int it = 0; it < 4; ++it) {
                const float* wp = wbase + it * 96 + i * 3;
                a0[it] += dm * wp[0];
                a1[it] += d0 * wp[1];
                a2[it] += dp * wp[2];
            }
        }
        int l = l0 + ll;
        #pragma unroll
        for (int it = 0; it < 4; ++it) {
            int o = (g << 5) + (os << 2) + it;
            x1[((b * CC + o) << 9) + l] = gelu_exact(a0[it] + a1[it] + a2[it] + b1[o]);
        }
    } else {
        int idx = ((blk - 256) << 8) + tid;   // 768*256 = 196608 = C*C*3
        int o  = idx / 768;
        int ck = idx - o * 768;
        w2t[ck * CC + o] = w2[idx];
    }
}

// ---------------- K2: fused dense conv1d (+bias+GELU) + depthwise band blur.
//  512 blocks: b(2) x oc(4) x lt(64). Each block computes x2 for its 64
//  output channels at 12 positions (l0-2 .. l0+9, incl. halo) from x1 only,
//  then writes the 5-float band rows over K1's zeros. No x2 global buffer.
__global__ __launch_bounds__(256) void k2(
    const float* __restrict__ x1, const float* __restrict__ w2t,
    const float* __restrict__ b2, const float* __restrict__ wb,
    float* __restrict__ out)
{
    __shared__ float s1[CC][14];    // x1[c][l0-3 .. l0+10]
    __shared__ float s2[64][13];    // x2[o][l0-2 .. l0+9], padded stride 13
    const int tid = threadIdx.x;
    const int blk = blockIdx.x;
    int oc = blk & 3;
    int lt = (blk >> 2) & 63;
    int b  = blk >> 8;
    int l0 = lt << 3;

    for (int t = tid; t < CC * 14; t += 256) {
        int c = t / 14;
        int j = t - c * 14;
        int p = l0 + j - 3;
        s1[c][j] = (p >= 0 && p < LL) ? x1[((b * CC + c) << 9) + p] : 0.0f;
    }
    __syncthreads();

    int ol = tid & 63;              // lane: output channel within chunk
    int jg = tid >> 6;              // wave-uniform position group
    int o  = (oc << 6) + ol;
    float bias = b2[o];
    float acc[3];
    #pragma unroll
    for (int r = 0; r < 3; ++r) acc[r] = bias;
    const float* wp = w2t + o;
    #pragma unroll 4
    for (int c = 0; c < CC; ++c) {
        float w0  = wp[c * 768];
        float w1v = wp[c * 768 + 256];
        float w2v = wp[c * 768 + 512];
        // positions p_r = jg*3 + r; x1 taps at s1[c][p_r + k]
        float t0 = s1[c][jg * 3 + 0];
        float t1 = s1[c][jg * 3 + 1];
        float t2 = s1[c][jg * 3 + 2];
        float t3 = s1[c][jg * 3 + 3];
        float t4 = s1[c][jg * 3 + 4];
        acc[0] += t0 * w0 + t1 * w1v + t2 * w2v;
        acc[1] += t1 * w0 + t2 * w1v + t3 * w2v;
        acc[2] += t2 * w0 + t3 * w1v + t4 * w2v;
    }
    #pragma unroll
    for (int r = 0; r < 3; ++r) {
        int p = l0 - 2 + jg * 3 + r;                 // global x2 position
        s2[ol][jg * 3 + r] = (p >= 0 && p < LL) ? gelu_exact(acc[r]) : 0.0f;
    }
    __syncthreads();

    // band write: thread (ol, jg) handles rows i = l0 + jg*2 + {0,1}
    const float* w = wb + ((b ? o : o)) * 9;  // channel = o (depthwise), same for both b
    const float* wc = wb + o * 9;
    (void)w;
    #pragma unroll
    for (int r2 = 0; r2 < 2; ++r2) {
        int i  = l0 + (jg << 1) + r2;
        int li = (jg << 1) + r2;                     // i - l0
        float xm = s2[ol][li + 1];                   // x2[i-1] (0 if OOB)
        float x0 = s2[ol][li + 2];                   // x2[i]
        float xp = s2[ol][li + 3];                   // x2[i+1]
        float v0 = wc[2] * xm;                        // j = i-2
        float v1 = wc[1] * xm + wc[5] * x0;           // j = i-1
        float v2 = wc[0] * xm + wc[4] * x0 + wc[8] * xp; // j = i
        float v3 = wc[3] * x0 + wc[7] * xp;           // j = i+1
        float v4 = wc[6] * xp;                        // j = i+2
        float* rowp = out + (((long long)(b * CC + o) << 9) + i) * LL;
        if (i >= 2)      rowp[i - 2] = v0;
        if (i >= 1)      rowp[i - 1] = v1;
        rowp[i] = v2;
        if (i <= LL - 2) rowp[i + 1] = v3;
        if (i <= LL - 3) rowp[i + 2] = v4;
    }
}

extern "C" void kernel_launch(void* const* d_in, const int* in_sizes, int n_in,
                              void* d_out, int out_size, void* d_ws, size_t ws_size,
                              hipStream_t stream) {
    const float* feat   = (const float*)d_in[0];
    const float* w1     = (const float*)d_in[1];
    const float* b1     = (const float*)d_in[2];
    const float* w2     = (const float*)d_in[3];
    const float* b2     = (const float*)d_in[4];
    const float* w_blur = (const float*)d_in[5];
    float* ws = (float*)d_ws;

    const int N = BB * CC * LL;      // 262144
    float* x1  = ws;                 // [N]
    float* w2t = ws + N;             // [C*C*3]

    k1<<<1024 + N4 / 256, 256, 0, stream>>>(feat, w1, b1, w2, x1, w2t, (v4f*)d_out);
    k2<<<512, 256, 0, stream>>>(x1, w2t, b2, w_blur, (float*)d_out);
}

// Round 10
// 169.553 us; speedup vs baseline: 1.0982x; 1.0982x over previous
//
#include <hip/hip_runtime.h>
#include <math.h>

#define BB 2
#define CC 256
#define LL 512        // H == W == L
#define N4 33554432   // output float4 quads
#define H4 16777216   // half the quads

typedef float v4f __attribute__((ext_vector_type(4)));

__device__ __forceinline__ float gelu_exact(float x) {
    return 0.5f * x * (1.0f + erff(x * 0.70710678118654752f));
}

// band-quad range for row i: quads [qlo, qhi] contain all j with |j-i|<=2
__device__ __forceinline__ void band_quads(int i, int& qlo, int& qhi) {
    int jlo = i - 2; if (jlo < 0) jlo = 0;
    int jhi = i + 2; if (jhi > LL - 1) jhi = LL - 1;
    qlo = jlo >> 2;
    qhi = jhi >> 2;
}

// ---------------- K1: fused diag-gather + grouped conv1 (+GELU) -> x1,
//                  w2 transpose -> w2t, zero quads [0, H4) minus band --------
__global__ __launch_bounds__(256) void k1(
    const float* __restrict__ feat, const float* __restrict__ w1,
    const float* __restrict__ b1, const float* __restrict__ w2,
    float* __restrict__ x1, float* __restrict__ w2t, v4f* __restrict__ out)
{
    const int tid = threadIdx.x;
    const int blk = blockIdx.x;
    if (blk >= 1024) {                        // zero blocks: one thread = one quad
        int idx4 = (blk - 1024) * 256 + tid;  // [0, H4)
        int i = (idx4 >> 7) & (LL - 1);
        int q = idx4 & 127;
        int qlo, qhi; band_quads(i, qlo, qhi);
        if (q < qlo || q > qhi)
            __builtin_nontemporal_store((v4f)(0.f), &out[idx4]);
        return;
    }
    if (blk < 256) {
        __shared__ float sg[32][34];
        int b  = blk >> 7;
        int g  = (blk >> 4) & 7;
        int l0 = (blk & 15) << 5;
        for (int t = tid; t < 32 * 34; t += 256) {
            int ch = t / 34;
            int j  = t - ch * 34;
            int l  = l0 + j - 1;
            int c  = (g << 5) + ch;
            sg[ch][j] = (l >= 0 && l < LL) ? feat[((b * CC + c) * LL + l) * LL + l] : 0.f;
        }
        __syncthreads();
        int ll = tid & 31;
        int os = tid >> 5;
        float a0[4] = {0.f, 0.f, 0.f, 0.f};
        float a1[4] = {0.f, 0.f, 0.f, 0.f};
        float a2[4] = {0.f, 0.f, 0.f, 0.f};
        const float* wbase = w1 + ((g << 5) + (os << 2)) * 96;
        #pragma unroll
        for (int i = 0; i < 32; ++i) {
            float dm = sg[i][ll];
            float d0 = sg[i][ll + 1];
            float dp = sg[i][ll + 2];
            #pragma unroll
            for (int it = 0; it < 4; ++it) {
                const float* wp = wbase + it * 96 + i * 3;
                a0[it] += dm * wp[0];
                a1[it] += d0 * wp[1];
                a2[it] += dp * wp[2];
            }
        }
        int l = l0 + ll;
        #pragma unroll
        for (int it = 0; it < 4; ++it) {
            int o = (g << 5) + (os << 2) + it;
            x1[((b * CC + o) << 9) + l] = gelu_exact(a0[it] + a1[it] + a2[it] + b1[o]);
        }
    } else {
        int idx = ((blk - 256) << 8) + tid;   // 768*256 = 196608 = C*C*3
        int o  = idx / 768;
        int ck = idx - o * 768;
        w2t[ck * CC + o] = w2[idx];
    }
}

// ---------------- K2: fused dense conv1d (+bias+GELU) + band-quad writer
//  (blocks 0..511), plus zero of quads [H4, N4) minus band (remaining blocks).
__global__ __launch_bounds__(256) void k2(
    const float* __restrict__ x1, const float* __restrict__ w2t,
    const float* __restrict__ b2, const float* __restrict__ wb,
    v4f* __restrict__ out)
{
    const int tid = threadIdx.x;
    const int blk = blockIdx.x;
    if (blk >= 512) {
        int idx4 = H4 + (blk - 512) * 256 + tid;   // [H4, N4)
        int i = (idx4 >> 7) & (LL - 1);
        int q = idx4 & 127;
        int qlo, qhi; band_quads(i, qlo, qhi);
        if (q < qlo || q > qhi)
            __builtin_nontemporal_store((v4f)(0.f), &out[idx4]);
        return;
    }
    __shared__ float s1[CC][14];    // x1[c][l0-3 .. l0+10]
    __shared__ float s2[64][13];    // x2[o][l0-2 .. l0+9], padded stride 13
    int oc = blk & 3;
    int lt = (blk >> 2) & 63;
    int b  = blk >> 8;
    int l0 = lt << 3;

    for (int t = tid; t < CC * 14; t += 256) {
        int c = t / 14;
        int j = t - c * 14;
        int p = l0 + j - 3;
        s1[c][j] = (p >= 0 && p < LL) ? x1[((b * CC + c) << 9) + p] : 0.0f;
    }
    __syncthreads();

    int ol = tid & 63;              // output channel within chunk
    int jg = tid >> 6;              // wave-uniform position group
    int o  = (oc << 6) + ol;
    float bias = b2[o];
    float acc[3];
    #pragma unroll
    for (int r = 0; r < 3; ++r) acc[r] = bias;
    const float* wp = w2t + o;
    #pragma unroll 4
    for (int c = 0; c < CC; ++c) {
        float w0  = wp[c * 768];
        float w1v = wp[c * 768 + 256];
        float w2v = wp[c * 768 + 512];
        float t0 = s1[c][jg * 3 + 0];
        float t1 = s1[c][jg * 3 + 1];
        float t2 = s1[c][jg * 3 + 2];
        float t3 = s1[c][jg * 3 + 3];
        float t4 = s1[c][jg * 3 + 4];
        acc[0] += t0 * w0 + t1 * w1v + t2 * w2v;
        acc[1] += t1 * w0 + t2 * w1v + t3 * w2v;
        acc[2] += t2 * w0 + t3 * w1v + t4 * w2v;
    }
    #pragma unroll
    for (int r = 0; r < 3; ++r) {
        int p = l0 - 2 + jg * 3 + r;                 // global x2 position
        s2[ol][jg * 3 + r] = (p >= 0 && p < LL) ? gelu_exact(acc[r]) : 0.0f;
    }
    __syncthreads();

    // band-quad write: thread (ol, jg) handles rows i = l0 + jg*2 + {0,1}
    const float* wc = wb + o * 9;   // w_blur[o,0,ki,kj] (depthwise)
    int bc = b * CC + o;
    #pragma unroll
    for (int r2 = 0; r2 < 2; ++r2) {
        int i  = l0 + (jg << 1) + r2;
        int li = (jg << 1) + r2;                     // i - l0
        float xm = s2[ol][li + 1];                   // x2[i-1] (0 if OOB)
        float x0 = s2[ol][li + 2];                   // x2[i]
        float xp = s2[ol][li + 3];                   // x2[i+1]
        float v0 = wc[2] * xm;                          // j = i-2
        float v1 = wc[1] * xm + wc[5] * x0;             // j = i-1
        float v2 = wc[0] * xm + wc[4] * x0 + wc[8] * xp;// j = i
        float v3 = wc[3] * x0 + wc[7] * xp;             // j = i+1
        float v4 = wc[6] * xp;                          // j = i+2
        int qlo, qhi; band_quads(i, qlo, qhi);
        int rowq = ((bc << 9) + i) << 7;             // quad index of row start
        for (int q = qlo; q <= qhi; ++q) {
            v4f v;
            #pragma unroll
            for (int t = 0; t < 4; ++t) {
                int d = (q << 2) + t - i;
                float r = 0.f;
                if (d == -2)      r = v0;
                else if (d == -1) r = v1;
                else if (d == 0)  r = v2;
                else if (d == 1)  r = v3;
                else if (d == 2)  r = v4;
                v[t] = r;
            }
            __builtin_nontemporal_store(v, &out[rowq + q]);
        }
    }
}

extern "C" void kernel_launch(void* const* d_in, const int* in_sizes, int n_in,
                              void* d_out, int out_size, void* d_ws, size_t ws_size,
                              hipStream_t stream) {
    const float* feat   = (const float*)d_in[0];
    const float* w1     = (const float*)d_in[1];
    const float* b1     = (const float*)d_in[2];
    const float* w2     = (const float*)d_in[3];
    const float* b2     = (const float*)d_in[4];
    const float* w_blur = (const float*)d_in[5];
    float* ws = (float*)d_ws;

    const int N = BB * CC * LL;      // 262144
    float* x1  = ws;                 // [N]
    float* w2t = ws + N;             // [C*C*3]

    k1<<<1024 + H4 / 256, 256, 0, stream>>>(feat, w1, b1, w2, x1, w2t, (v4f*)d_out);
    k2<<<512 + H4 / 256, 256, 0, stream>>>(x1, w2t, b2, w_blur, (v4f*)d_out);
}

// Round 11
// 154.937 us; speedup vs baseline: 1.2018x; 1.0943x over previous
//
#include <hip/hip_runtime.h>
#include <math.h>

#define BB 2
#define CC 256
#define LL 512        // H == W == L

// quad partition of the 2^25 output float4s (exact, from R8)
#define N4       33554432
#define A_QUADS  11184896   // K1 zeros [0, A)        = 43691*256
#define B_QUADS  22369792   // K2 zeros [A, B)        = +43691*256
#define ZBLK     43691
#define ZBLK3    43690      // K3 zeros [B, N4)       = 43690*256 exactly

typedef float v4f __attribute__((ext_vector_type(4)));

__device__ __forceinline__ float gelu_exact(float x) {
    return 0.5f * x * (1.0f + erff(x * 0.70710678118654752f));
}

// ---------------- K1: fused diag-gather + grouped conv1 (+GELU) -> x1,
//                  w2 transpose -> w2t, zero quads [0, A) --------------------
__global__ __launch_bounds__(256) void k1(
    const float* __restrict__ feat, const float* __restrict__ w1,
    const float* __restrict__ b1, const float* __restrict__ w2,
    float* __restrict__ x1, float* __restrict__ w2t, v4f* __restrict__ out)
{
    const int tid = threadIdx.x;
    const int blk = blockIdx.x;
    if (blk >= 1024) {                       // zero blocks: one thread = one quad
        int idx4 = (blk - 1024) * 256 + tid; // [0, A)
        __builtin_nontemporal_store((v4f)(0.f), &out[idx4]);
        return;
    }
    if (blk < 256) {
        __shared__ float sg[32][34];
        int b  = blk >> 7;
        int g  = (blk >> 4) & 7;
        int l0 = (blk & 15) << 5;
        for (int t = tid; t < 32 * 34; t += 256) {
            int ch = t / 34;
            int j  = t - ch * 34;
            int l  = l0 + j - 1;
            int c  = (g << 5) + ch;
            sg[ch][j] = (l >= 0 && l < LL) ? feat[((b * CC + c) * LL + l) * LL + l] : 0.f;
        }
        __syncthreads();
        int ll = tid & 31;
        int os = tid >> 5;
        float a0[4] = {0.f, 0.f, 0.f, 0.f};
        float a1[4] = {0.f, 0.f, 0.f, 0.f};
        float a2[4] = {0.f, 0.f, 0.f, 0.f};
        const float* wbase = w1 + ((g << 5) + (os << 2)) * 96;
        #pragma unroll
        for (int i = 0; i < 32; ++i) {
            float dm = sg[i][ll];
            float d0 = sg[i][ll + 1];
            float dp = sg[i][ll + 2];
            #pragma unroll
            for (int it = 0; it < 4; ++it) {
                const float* wp = wbase + it * 96 + i * 3;
                a0[it] += dm * wp[0];
                a1[it] += d0 * wp[1];
                a2[it] += dp * wp[2];
            }
        }
        int l = l0 + ll;
        #pragma unroll
        for (int it = 0; it < 4; ++it) {
            int o = (g << 5) + (os << 2) + it;
            x1[((b * CC + o) << 9) + l] = gelu_exact(a0[it] + a1[it] + a2[it] + b1[o]);
        }
    } else {
        int idx = ((blk - 256) << 8) + tid;   // 768*256 = 196608 = C*C*3
        int o  = idx / 768;
        int ck = idx - o * 768;
        w2t[ck * CC + o] = w2[idx];
    }
}

// ---------------- K2: dense conv1d (+bias+GELU) -> x2, zero quads [A, B) ----
__global__ __launch_bounds__(256) void k2(
    const float* __restrict__ x1, const float* __restrict__ w2t,
    const float* __restrict__ b2, float* __restrict__ x2, v4f* __restrict__ out)
{
    const int tid = threadIdx.x;
    const int blk = blockIdx.x;
    if (blk >= 512) {
        int idx4 = A_QUADS + (blk - 512) * 256 + tid;  // [A, B)
        __builtin_nontemporal_store((v4f)(0.f), &out[idx4]);
        return;
    }
    __shared__ float s[CC][10];
    int oc = blk & 3;
    int lt = (blk >> 2) & 63;
    int b  = blk >> 8;
    int l0 = lt << 3;
    for (int t = tid; t < CC * 10; t += 256) {
        int c = t / 10;
        int j = t - c * 10;
        int p = l0 + j - 1;
        s[c][j] = (p >= 0 && p < LL) ? x1[((b * CC + c) << 9) + p] : 0.0f;
    }
    __syncthreads();
    int o  = (oc << 6) + (tid & 63);
    int jg = tid >> 6;
    float bias = b2[o];
    float acc0 = bias, acc1 = bias;
    const float* wp = w2t + o;
    #pragma unroll 4
    for (int c = 0; c < CC; ++c) {
        float w0  = wp[c * 768];
        float w1v = wp[c * 768 + 256];
        float w2v = wp[c * 768 + 512];
        float s0 = s[c][jg * 2 + 0];
        float s1 = s[c][jg * 2 + 1];
        float s2 = s[c][jg * 2 + 2];
        float s3 = s[c][jg * 2 + 3];
        acc0 += s0 * w0 + s1 * w1v + s2 * w2v;
        acc1 += s1 * w0 + s2 * w1v + s3 * w2v;
    }
    int l = l0 + jg * 2;
    float* xo = x2 + ((b * CC + o) << 9) + l;
    xo[0] = gelu_exact(acc0);
    xo[1] = gelu_exact(acc1);
}

// ---------------- K3: pure zero of quads [B, N4) — no predicate, no branch --
__global__ __launch_bounds__(256) void k3(v4f* __restrict__ out)
{
    int idx4 = B_QUADS + blockIdx.x * 256 + threadIdx.x;
    __builtin_nontemporal_store((v4f)(0.f), &out[idx4]);
}

// ---------------- K4: band overwrite for ALL rows (over the zeros) ----------
__global__ __launch_bounds__(256) void k4(
    const float* __restrict__ x2, const float* __restrict__ wb,
    float* __restrict__ outf)
{
    int row = blockIdx.x * 256 + threadIdx.x;   // bc*512 + i, < 262144
    int i  = row & (LL - 1);
    int bc = row >> 9;
    const float* xr = x2 + (bc << 9);
    float xm = (i > 0)      ? xr[i - 1] : 0.f;
    float x0 = xr[i];
    float xp = (i < LL - 1) ? xr[i + 1] : 0.f;
    const float* w = wb + (bc & (CC - 1)) * 9;    // w_blur[c,0,ki,kj]
    float v0 = w[2] * xm;                         // j = i-2
    float v1 = w[1] * xm + w[5] * x0;             // j = i-1
    float v2 = w[0] * xm + w[4] * x0 + w[8] * xp; // j = i
    float v3 = w[3] * x0 + w[7] * xp;             // j = i+1
    float v4 = w[6] * xp;                         // j = i+2
    float* r = outf + ((long long)row << 9);
    if (i >= 2)      r[i - 2] = v0;
    if (i >= 1)      r[i - 1] = v1;
    r[i] = v2;
    if (i <= LL - 2) r[i + 1] = v3;
    if (i <= LL - 3) r[i + 2] = v4;
}

extern "C" void kernel_launch(void* const* d_in, const int* in_sizes, int n_in,
                              void* d_out, int out_size, void* d_ws, size_t ws_size,
                              hipStream_t stream) {
    const float* feat   = (const float*)d_in[0];
    const float* w1     = (const float*)d_in[1];
    const float* b1     = (const float*)d_in[2];
    const float* w2     = (const float*)d_in[3];
    const float* b2     = (const float*)d_in[4];
    const float* w_blur = (const float*)d_in[5];
    float* ws = (float*)d_ws;

    const int N = BB * CC * LL;      // 262144
    float* x1  = ws;                 // [N]
    float* x2  = ws + N;             // [N]
    float* w2t = ws + 2 * N;         // [C*C*3]

    k1<<<1024 + ZBLK, 256, 0, stream>>>(feat, w1, b1, w2, x1, w2t, (v4f*)d_out);
    k2<<<512 + ZBLK, 256, 0, stream>>>(x1, w2t, b2, x2, (v4f*)d_out);
    k3<<<ZBLK3, 256, 0, stream>>>((v4f*)d_out);
    k4<<<1024, 256, 0, stream>>>(x2, w_blur, (float*)d_out);
}

// Round 12
// 152.942 us; speedup vs baseline: 1.2175x; 1.0130x over previous
//
#include <hip/hip_runtime.h>
#include <math.h>

#define BB 2
#define CC 256
#define LL 512        // H == W == L

// exact quad partition of the 2^25 output float4s
#define N4       33554432
#define ZBLK12   48900              // zero blocks in k1 and k2 (each 48900*256 quads)
#define A_QUADS  12518400           // = ZBLK12*256      k1 zeros [0, A)
#define B_QUADS  25036800           // = 2*ZBLK12*256    k2 zeros [A, B)
#define FBLK     33272              // k3 fused covers [B, N4) = 33272*256 exactly
#define ROWS_BANDED 195600          // rows with all quads < B  (= B/128)
#define BANDBLK  765                // ceil(ROWS_BANDED/256)

typedef float v4f __attribute__((ext_vector_type(4)));

__device__ __forceinline__ float gelu_exact(float x) {
    return 0.5f * x * (1.0f + erff(x * 0.70710678118654752f));
}

// ---------------- K1: fused diag-gather + grouped conv1 (+GELU) -> x1,
//                  w2 transpose -> w2t, zero quads [0, A) --------------------
__global__ __launch_bounds__(256) void k1(
    const float* __restrict__ feat, const float* __restrict__ w1,
    const float* __restrict__ b1, const float* __restrict__ w2,
    float* __restrict__ x1, float* __restrict__ w2t, v4f* __restrict__ out)
{
    const int tid = threadIdx.x;
    const int blk = blockIdx.x;
    if (blk >= 1024) {                       // zero blocks: one thread = one quad
        int idx4 = (blk - 1024) * 256 + tid; // [0, A)
        __builtin_nontemporal_store((v4f)(0.f), &out[idx4]);
        return;
    }
    if (blk < 256) {
        __shared__ float sg[32][34];
        int b  = blk >> 7;
        int g  = (blk >> 4) & 7;
        int l0 = (blk & 15) << 5;
        for (int t = tid; t < 32 * 34; t += 256) {
            int ch = t / 34;
            int j  = t - ch * 34;
            int l  = l0 + j - 1;
            int c  = (g << 5) + ch;
            sg[ch][j] = (l >= 0 && l < LL) ? feat[((b * CC + c) * LL + l) * LL + l] : 0.f;
        }
        __syncthreads();
        int ll = tid & 31;
        int os = tid >> 5;
        float a0[4] = {0.f, 0.f, 0.f, 0.f};
        float a1[4] = {0.f, 0.f, 0.f, 0.f};
        float a2[4] = {0.f, 0.f, 0.f, 0.f};
        const float* wbase = w1 + ((g << 5) + (os << 2)) * 96;
        #pragma unroll
        for (int i = 0; i < 32; ++i) {
            float dm = sg[i][ll];
            float d0 = sg[i][ll + 1];
            float dp = sg[i][ll + 2];
            #pragma unroll
            for (int it = 0; it < 4; ++it) {
                const float* wp = wbase + it * 96 + i * 3;
                a0[it] += dm * wp[0];
                a1[it] += d0 * wp[1];
                a2[it] += dp * wp[2];
            }
        }
        int l = l0 + ll;
        #pragma unroll
        for (int it = 0; it < 4; ++it) {
            int o = (g << 5) + (os << 2) + it;
            x1[((b * CC + o) << 9) + l] = gelu_exact(a0[it] + a1[it] + a2[it] + b1[o]);
        }
    } else {
        int idx = ((blk - 256) << 8) + tid;   // 768*256 = 196608 = C*C*3
        int o  = idx / 768;
        int ck = idx - o * 768;
        w2t[ck * CC + o] = w2[idx];
    }
}

// ---------------- K2: dense conv1d (+bias+GELU) -> x2, zero quads [A, B) ----
__global__ __launch_bounds__(256) void k2(
    const float* __restrict__ x1, const float* __restrict__ w2t,
    const float* __restrict__ b2, float* __restrict__ x2, v4f* __restrict__ out)
{
    const int tid = threadIdx.x;
    const int blk = blockIdx.x;
    if (blk >= 512) {
        int idx4 = A_QUADS + (blk - 512) * 256 + tid;  // [A, B)
        __builtin_nontemporal_store((v4f)(0.f), &out[idx4]);
        return;
    }
    __shared__ float s[CC][10];
    int oc = blk & 3;
    int lt = (blk >> 2) & 63;
    int b  = blk >> 8;
    int l0 = lt << 3;
    for (int t = tid; t < CC * 10; t += 256) {
        int c = t / 10;
        int j = t - c * 10;
        int p = l0 + j - 1;
        s[c][j] = (p >= 0 && p < LL) ? x1[((b * CC + c) << 9) + p] : 0.0f;
    }
    __syncthreads();
    int o  = (oc << 6) + (tid & 63);
    int jg = tid >> 6;
    float bias = b2[o];
    float acc0 = bias, acc1 = bias;
    const float* wp = w2t + o;
    #pragma unroll 4
    for (int c = 0; c < CC; ++c) {
        float w0  = wp[c * 768];
        float w1v = wp[c * 768 + 256];
        float w2v = wp[c * 768 + 512];
        float s0 = s[c][jg * 2 + 0];
        float s1 = s[c][jg * 2 + 1];
        float s2 = s[c][jg * 2 + 2];
        float s3 = s[c][jg * 2 + 3];
        acc0 += s0 * w0 + s1 * w1v + s2 * w2v;
        acc1 += s1 * w0 + s2 * w1v + s3 * w2v;
    }
    int l = l0 + jg * 2;
    float* xo = x2 + ((b * CC + o) << 9) + l;
    xo[0] = gelu_exact(acc0);
    xo[1] = gelu_exact(acc1);
}

// ---------------- K3: band full-line writes for rows < ROWS_BANDED (over the
//  zeros from k1/k2), plus fused zero-or-band stream for quads [B, N4) -------
__global__ __launch_bounds__(256) void k3(
    const float* __restrict__ x2, const float* __restrict__ wb,
    v4f* __restrict__ out)
{
    const int tid = threadIdx.x;
    const int blk = blockIdx.x;
    if (blk < BANDBLK) {
        int row = blk * 256 + tid;           // bc*512 + i
        if (row >= ROWS_BANDED) return;
        int i  = row & (LL - 1);
        int bc = row >> 9;
        const float* xr = x2 + (bc << 9);
        float xm = (i > 0)      ? xr[i - 1] : 0.f;
        float x0 = xr[i];
        float xp = (i < LL - 1) ? xr[i + 1] : 0.f;
        const float* w = wb + (bc & (CC - 1)) * 9;    // w_blur[c,0,ki,kj]
        float bv[5];
        bv[0] = w[2] * xm;                            // j = i-2
        bv[1] = w[1] * xm + w[5] * x0;                // j = i-1
        bv[2] = w[0] * xm + w[4] * x0 + w[8] * xp;    // j = i
        bv[3] = w[3] * x0 + w[7] * xp;                // j = i+1
        bv[4] = w[6] * xp;                            // j = i+2
        int jlo = (i >= 2) ? i - 2 : 0;
        int jhi = (i <= LL - 3) ? i + 2 : LL - 1;
        int Llo = jlo >> 4;                           // 16-float (64 B) lines
        int Lhi = jhi >> 4;
        int rowq = row << 7;                          // quad index of row start
        for (int L = Llo; L <= Lhi; ++L) {
            float line[16];
            #pragma unroll
            for (int t = 0; t < 16; ++t) line[t] = 0.f;
            int base = L << 4;
            #pragma unroll
            for (int d = 0; d < 5; ++d) {
                int j = i - 2 + d;
                int t = j - base;
                if (j >= jlo && j <= jhi && t >= 0 && t < 16) line[t] = bv[d];
            }
            #pragma unroll
            for (int q = 0; q < 4; ++q) {
                v4f v;
                v[0] = line[q * 4 + 0]; v[1] = line[q * 4 + 1];
                v[2] = line[q * 4 + 2]; v[3] = line[q * 4 + 3];
                __builtin_nontemporal_store(v, &out[rowq + (L << 2) + q]);
            }
        }
        return;
    }
    // fused zero-or-band for quads [B, N4)
    int idx4 = B_QUADS + (blk - BANDBLK) * 256 + tid;
    int row = idx4 >> 7;
    int i   = row & (LL - 1);
    int d0  = ((idx4 & 127) << 2) - i;
    v4f v = (v4f)(0.f);
    if ((unsigned)(d0 + 5) <= 7u) {
        int bc = row >> 9;
        const float* xr = x2 + (bc << 9);
        float xm = (i > 0)      ? xr[i - 1] : 0.f;
        float x0 = xr[i];
        float xp = (i < LL - 1) ? xr[i + 1] : 0.f;
        const float* w = wb + (bc & (CC - 1)) * 9;
        #pragma unroll
        for (int t = 0; t < 4; ++t) {
            int d = d0 + t;
            float r = 0.f;
            if (d == -2)      r = w[2] * xm;
            else if (d == -1) r = w[1] * xm + w[5] * x0;
            else if (d == 0)  r = w[0] * xm + w[4] * x0 + w[8] * xp;
            else if (d == 1)  r = w[3] * x0 + w[7] * xp;
            else if (d == 2)  r = w[6] * xp;
            v[t] = r;
        }
    }
    __builtin_nontemporal_store(v, &out[idx4]);
}

extern "C" void kernel_launch(void* const* d_in, const int* in_sizes, int n_in,
                              void* d_out, int out_size, void* d_ws, size_t ws_size,
                              hipStream_t stream) {
    const float* feat   = (const float*)d_in[0];
    const float* w1     = (const float*)d_in[1];
    const float* b1     = (const float*)d_in[2];
    const float* w2     = (const float*)d_in[3];
    const float* b2     = (const float*)d_in[4];
    const float* w_blur = (const float*)d_in[5];
    float* ws = (float*)d_ws;

    const int N = BB * CC * LL;      // 262144
    float* x1  = ws;                 // [N]
    float* x2  = ws + N;             // [N]
    float* w2t = ws + 2 * N;         // [C*C*3]

    k1<<<1024 + ZBLK12, 256, 0, stream>>>(feat, w1, b1, w2, x1, w2t, (v4f*)d_out);
    k2<<<512 + ZBLK12, 256, 0, stream>>>(x1, w2t, b2, x2, (v4f*)d_out);
    k3<<<BANDBLK + FBLK, 256, 0, stream>>>(x2, w_blur, (v4f*)d_out);
}